// Round 14
// baseline (52.004 us; speedup 1.0000x reference)
//
#include <hip/hip_runtime.h>

// G=14, B=64, T=2048, H=6
#define Gc 14
#define Hc 6
#define NPc (64*2048)          // B*T points
#define LOG_2PI 1.8378770664093453f

typedef float v2f __attribute__((ext_vector_type(2)));

__device__ __forceinline__ float frsq(float x){ return __builtin_amdgcn_rsqf(x); }

// DPP quad_perm broadcast within lane pairs (1-cycle VALU, no LDS):
//   0xA0 = [0,0,2,2] -> pair gets EVEN lane's value; 0xF5 = [1,1,3,3] -> ODD lane's.
template<int CTRL>
__device__ __forceinline__ float dppf(float x){
    union { float f; int i; } u; u.f = x;
    u.i = __builtin_amdgcn_update_dpp(0, u.i, CTRL, 0xF, 0xF, true);
    return u.f;
}
template<int OQ>
__device__ __forceinline__ float bcast(float x){
    return (OQ == 0) ? dppf<0xA0>(x) : dppf<0xF5>(x);
}

// Nontemporal 8-byte store (keep the 22 MB output stream out of L2/L3 so the
// input set stays cache-resident across replays). (R11 win)
__device__ __forceinline__ void nt_store_v2f(float* p, v2f v){
    union { v2f f; unsigned long long u; } c; c.f = v;
    __builtin_nontemporal_store(c.u, (unsigned long long*)p);
}

// One sweep of N-1 chained gprods.
// Head channel = component C of v2f J on owner lane OQ (cur on lane0 / nxt on lane1).
// Identities (|r*C|==1): x3 = a1*x1 - a2*x2 ; x4 = s2*x1 + s1*x2, with
//   S = rsqrt(C1^2+C2^2), s1=C2*S, s2=C1*S, a1=copysign(s1,C1), a2=copysign(s2,C2).
// logC == 0 exactly -> dropped. Head channel gets x4 = sqrt(C1^2+C2^2) = 1/std4. OK.
// Lane0 st = cur, lane1 st = nxt (one uniform packed stream serves both arrays);
// bb duplicated & bit-identical on both lanes.
template<int J, int C, int N, int OQ>
__device__ __forceinline__ void sweep(v2f (&st)[Gc][3], float (&bb)[Gc]){
#pragma unroll
    for (int i = 0; i < N - 1; ++i){
        const float C1 = bcast<OQ>(st[i][J][C]);
        const float C2 = bcast<OQ>(st[i + 1][J][C]);
        const float S  = frsq(fmaf(C1, C1, C2 * C2));   // 1 transcendental per gprod
        const float s1 = C2 * S, s2 = C1 * S;
        const float a1 = copysignf(s1, C1), a2 = copysignf(s2, C2);
        const v2f A1 = {a1, a1}, A2 = {a2, a2}, S1 = {s1, s1}, S2 = {s2, s2};
        // 3 packed channel-pair updates per slot pair
#pragma unroll
        for (int j = 0; j < 3; ++j){
            const v2f x = st[i][j], y = st[i + 1][j];
            st[i][j]     = __builtin_elementwise_fma(x, A1, -(y * A2));
            st[i + 1][j] = __builtin_elementwise_fma(x, S2, y * S1);
        }
        // bias channel (scalar; bit-identical on both lanes)
        {
            const float x = bb[i], y = bb[i + 1];
            bb[i]     = fmaf(x, a1, -(y * a2));
            bb[i + 1] = fmaf(x, s2, y * s1);
        }
    }
}

// R14: 64-thread blocks (1 wave each). Measured occupancy tracked BLOCK count
// across R3/R5/R7/R11/R13 (512 blk -> 9.5%, 1024 -> 16.5%, 2048 -> 31-44%):
// multi-wave blocks co-reside/retire as a unit and starve SIMDs. Single-wave
// blocks give the dispatcher 4096 independent units. (64,4): 4 waves/EU min
// -> same 128-VGPR tier as R11 (VGPR was 92).
__global__ void __launch_bounds__(64, 4)
gaussmerge_kernel(const float* __restrict__ cur_in,
                  const float* __restrict__ nxt_in,
                  const float* __restrict__ b_in,
                  float* __restrict__ out)
{
    const int tid = threadIdx.x;
    const int q = tid & 1;                          // 0: cur-owner, 1: nxt-owner
    const int p = blockIdx.x * 32 + (tid >> 1);     // point index

    v2f   st[Gc][3];
    float bb[Gc];

    const float* abase = (q ? nxt_in : cur_in) + (size_t)p * Hc;
    const float* bp    = b_in + p;
#pragma unroll
    for (int g = 0; g < Gc; ++g){
        // one 24-B record per lane: dwordx4 + dwordx2
        const float* rec = abase + (size_t)g * (NPc * Hc);
        const float4 A = *(const float4*)rec;
        const float2 B = *(const float2*)(rec + 4);
        st[g][0] = (v2f){A.x, A.y};
        st[g][1] = (v2f){A.z, A.w};
        st[g][2] = (v2f){B.x, B.y};
        bb[g] = bp[(size_t)g * NPc];
    }

    float LC = 0.0f;   // phase-1 log args valid on lane0 only; lane1's LC discarded

    // ---- phase 1: head = cur[k] (lane0); k -> (J=k>>1, C=k&1); n = 14-k ----
    sweep<0, 0, 14, 0>(st, bb); LC -= __logf(fabsf(st[13][0][0]));
    sweep<0, 1, 13, 0>(st, bb); LC -= __logf(fabsf(st[12][0][1]));
    sweep<1, 0, 12, 0>(st, bb); LC -= __logf(fabsf(st[11][1][0]));
    sweep<1, 1, 11, 0>(st, bb); LC -= __logf(fabsf(st[10][1][1]));
    sweep<2, 0, 10, 0>(st, bb); LC -= __logf(fabsf(st[ 9][2][0]));
    sweep<2, 1,  9, 0>(st, bb); LC -= __logf(fabsf(st[ 8][2][1]));

    // ---- phase 2: head = nxt[k] (lane1); n = 8-k; popped slot m = 7-k ----
    float* outN = out;                               // (6, B, T, H)
    float* outB = out + (size_t)Hc * NPc * Hc;       // (6, B, T)
    float* outL = outB + (size_t)Hc * NPc;           // (B, T)

#define PH2(K, J, C, N)                                                         \
    sweep<J, C, N, 1>(st, bb);                                                  \
    {                                                                           \
        constexpr int m = 7 - (K);                                              \
        if (q) {                                                                \
            float* o = outN + (size_t)(K) * (NPc * Hc) + (size_t)p * Hc;        \
            nt_store_v2f(o,     st[m][0]);                                      \
            nt_store_v2f(o + 2, st[m][1]);                                      \
            nt_store_v2f(o + 4, st[m][2]);                                      \
        } else {                                                                \
            __builtin_nontemporal_store(bb[m], outB + (size_t)(K) * NPc + p);   \
        }                                                                       \
    }

    PH2(0, 0, 0, 8)
    PH2(1, 0, 1, 7)
    PH2(2, 1, 0, 6)
    PH2(3, 1, 1, 5)
    PH2(4, 2, 0, 4)
    PH2(5, 2, 1, 3)
#undef PH2

    // ---- epilogue: remaining biases (slots 0,1; identical on both lanes) ----
    LC += -0.5f * (LOG_2PI + bb[0] * bb[0]);
    LC += -0.5f * (LOG_2PI + bb[1] * bb[1]);
    if (q == 0) __builtin_nontemporal_store(LC, outL + p);
}

extern "C" void kernel_launch(void* const* d_in, const int* in_sizes, int n_in,
                              void* d_out, int out_size, void* d_ws, size_t ws_size,
                              hipStream_t stream) {
    const float* cur = (const float*)d_in[0];
    const float* nxt = (const float*)d_in[1];
    const float* bia = (const float*)d_in[2];
    float* out = (float*)d_out;

    // 2 threads per point, 64-thread (single-wave) blocks: 32 points/block.
    dim3 grid((NPc * 2) / 64), block(64);
    gaussmerge_kernel<<<grid, block, 0, stream>>>(cur, nxt, bia, out);
}

// Round 15
// 29.973 us; speedup vs baseline: 1.7351x; 1.7351x over previous
//
#include <hip/hip_runtime.h>

// G=14, B=64, T=2048, H=6
#define Gc 14
#define Hc 6
#define NPc (64*2048)          // B*T points
#define LOG_2PI 1.8378770664093453f

typedef float v2f __attribute__((ext_vector_type(2)));

__device__ __forceinline__ float frsq(float x){ return __builtin_amdgcn_rsqf(x); }

// DPP quad_perm broadcast within lane pairs (1-cycle VALU, no LDS):
//   0xA0 = [0,0,2,2] -> pair gets EVEN lane's value; 0xF5 = [1,1,3,3] -> ODD lane's.
template<int CTRL>
__device__ __forceinline__ float dppf(float x){
    union { float f; int i; } u; u.f = x;
    u.i = __builtin_amdgcn_update_dpp(0, u.i, CTRL, 0xF, 0xF, true);
    return u.f;
}
template<int OQ>
__device__ __forceinline__ float bcast(float x){
    return (OQ == 0) ? dppf<0xA0>(x) : dppf<0xF5>(x);
}

// Nontemporal 8-byte store (keep the 22 MB output stream out of L2/L3 so the
// input set stays cache-resident across replays). (R11 win)
__device__ __forceinline__ void nt_store_v2f(float* p, v2f v){
    union { v2f f; unsigned long long u; } c; c.f = v;
    __builtin_nontemporal_store(c.u, (unsigned long long*)p);
}

// One sweep of N-1 chained gprods.
// Head channel = component C of v2f J on owner lane OQ (cur on lane0 / nxt on lane1).
// Identities (|r*C|==1): x3 = a1*x1 - a2*x2 ; x4 = s2*x1 + s1*x2, with
//   S = rsqrt(C1^2+C2^2), s1=C2*S, s2=C1*S, a1=copysign(s1,C1), a2=copysign(s2,C2).
// logC == 0 exactly -> dropped. Head channel gets x4 = sqrt(C1^2+C2^2) = 1/std4. OK.
// Lane0 st = cur, lane1 st = nxt (one uniform packed stream serves both arrays);
// bb duplicated & bit-identical on both lanes.
template<int J, int C, int N, int OQ>
__device__ __forceinline__ void sweep(v2f (&st)[Gc][3], float (&bb)[Gc]){
#pragma unroll
    for (int i = 0; i < N - 1; ++i){
        const float C1 = bcast<OQ>(st[i][J][C]);
        const float C2 = bcast<OQ>(st[i + 1][J][C]);
        const float S  = frsq(fmaf(C1, C1, C2 * C2));   // 1 transcendental per gprod
        const float s1 = C2 * S, s2 = C1 * S;
        const float a1 = copysignf(s1, C1), a2 = copysignf(s2, C2);
        const v2f A1 = {a1, a1}, A2 = {a2, a2}, S1 = {s1, s1}, S2 = {s2, s2};
        // 3 packed channel-pair updates per slot pair
#pragma unroll
        for (int j = 0; j < 3; ++j){
            const v2f x = st[i][j], y = st[i + 1][j];
            st[i][j]     = __builtin_elementwise_fma(x, A1, -(y * A2));
            st[i + 1][j] = __builtin_elementwise_fma(x, S2, y * S1);
        }
        // bias channel (scalar; bit-identical on both lanes)
        {
            const float x = bb[i], y = bb[i + 1];
            bb[i]     = fmaf(x, a1, -(y * a2));
            bb[i + 1] = fmaf(x, s2, y * s1);
        }
    }
}

// R15: single-wave blocks at the PROVEN register tier.
// Empirical toolchain rule (R4/R6/R12/R14): VGPR cap = 256 / min_waves_per_EU,
// independent of block size. (64,2) -> 128 cap (same tier as R11's VGPR=92).
// Theory under test: multi-wave blocks co-reside/retire as a unit; occupancy
// counter tracked BLOCK count (512->9.5%, 1024->16.5%, 2048->31-44%). 4096
// single-wave blocks give the dispatcher independent units to pack SIMDs and
// de-synchronize the load phase.
__global__ void __launch_bounds__(64, 2)
gaussmerge_kernel(const float* __restrict__ cur_in,
                  const float* __restrict__ nxt_in,
                  const float* __restrict__ b_in,
                  float* __restrict__ out)
{
    const int tid = threadIdx.x;
    const int q = tid & 1;                          // 0: cur-owner, 1: nxt-owner
    const int p = blockIdx.x * 32 + (tid >> 1);     // point index

    v2f   st[Gc][3];
    float bb[Gc];

    const float* abase = (q ? nxt_in : cur_in) + (size_t)p * Hc;
    const float* bp    = b_in + p;
#pragma unroll
    for (int g = 0; g < Gc; ++g){
        // one 24-B record per lane: dwordx4 + dwordx2
        const float* rec = abase + (size_t)g * (NPc * Hc);
        const float4 A = *(const float4*)rec;
        const float2 B = *(const float2*)(rec + 4);
        st[g][0] = (v2f){A.x, A.y};
        st[g][1] = (v2f){A.z, A.w};
        st[g][2] = (v2f){B.x, B.y};
        bb[g] = bp[(size_t)g * NPc];
    }

    float LC = 0.0f;   // phase-1 log args valid on lane0 only; lane1's LC discarded

    // ---- phase 1: head = cur[k] (lane0); k -> (J=k>>1, C=k&1); n = 14-k ----
    sweep<0, 0, 14, 0>(st, bb); LC -= __logf(fabsf(st[13][0][0]));
    sweep<0, 1, 13, 0>(st, bb); LC -= __logf(fabsf(st[12][0][1]));
    sweep<1, 0, 12, 0>(st, bb); LC -= __logf(fabsf(st[11][1][0]));
    sweep<1, 1, 11, 0>(st, bb); LC -= __logf(fabsf(st[10][1][1]));
    sweep<2, 0, 10, 0>(st, bb); LC -= __logf(fabsf(st[ 9][2][0]));
    sweep<2, 1,  9, 0>(st, bb); LC -= __logf(fabsf(st[ 8][2][1]));

    // ---- phase 2: head = nxt[k] (lane1); n = 8-k; popped slot m = 7-k ----
    float* outN = out;                               // (6, B, T, H)
    float* outB = out + (size_t)Hc * NPc * Hc;       // (6, B, T)
    float* outL = outB + (size_t)Hc * NPc;           // (B, T)

#define PH2(K, J, C, N)                                                         \
    sweep<J, C, N, 1>(st, bb);                                                  \
    {                                                                           \
        constexpr int m = 7 - (K);                                              \
        if (q) {                                                                \
            float* o = outN + (size_t)(K) * (NPc * Hc) + (size_t)p * Hc;        \
            nt_store_v2f(o,     st[m][0]);                                      \
            nt_store_v2f(o + 2, st[m][1]);                                      \
            nt_store_v2f(o + 4, st[m][2]);                                      \
        } else {                                                                \
            __builtin_nontemporal_store(bb[m], outB + (size_t)(K) * NPc + p);   \
        }                                                                       \
    }

    PH2(0, 0, 0, 8)
    PH2(1, 0, 1, 7)
    PH2(2, 1, 0, 6)
    PH2(3, 1, 1, 5)
    PH2(4, 2, 0, 4)
    PH2(5, 2, 1, 3)
#undef PH2

    // ---- epilogue: remaining biases (slots 0,1; identical on both lanes) ----
    LC += -0.5f * (LOG_2PI + bb[0] * bb[0]);
    LC += -0.5f * (LOG_2PI + bb[1] * bb[1]);
    if (q == 0) __builtin_nontemporal_store(LC, outL + p);
}

extern "C" void kernel_launch(void* const* d_in, const int* in_sizes, int n_in,
                              void* d_out, int out_size, void* d_ws, size_t ws_size,
                              hipStream_t stream) {
    const float* cur = (const float*)d_in[0];
    const float* nxt = (const float*)d_in[1];
    const float* bia = (const float*)d_in[2];
    float* out = (float*)d_out;

    // 2 threads per point, 64-thread (single-wave) blocks: 32 points/block.
    dim3 grid((NPc * 2) / 64), block(64);
    gaussmerge_kernel<<<grid, block, 0, stream>>>(cur, nxt, bia, out);
}

// Round 16
// 29.266 us; speedup vs baseline: 1.7769x; 1.0241x over previous
//
#include <hip/hip_runtime.h>

// G=14, B=64, T=2048, H=6
#define Gc 14
#define Hc 6
#define NPc (64*2048)          // B*T points
#define LOG_2PI 1.8378770664093453f

typedef float v2f __attribute__((ext_vector_type(2)));

__device__ __forceinline__ float frsq(float x){ return __builtin_amdgcn_rsqf(x); }

// DPP quad_perm broadcast within lane pairs (1-cycle VALU, no LDS):
//   0xA0 = [0,0,2,2] -> pair gets EVEN lane's value; 0xF5 = [1,1,3,3] -> ODD lane's.
template<int CTRL>
__device__ __forceinline__ float dppf(float x){
    union { float f; int i; } u; u.f = x;
    u.i = __builtin_amdgcn_update_dpp(0, u.i, CTRL, 0xF, 0xF, true);
    return u.f;
}
template<int OQ>
__device__ __forceinline__ float bcast(float x){
    return (OQ == 0) ? dppf<0xA0>(x) : dppf<0xF5>(x);
}

// Nontemporal stores: keep the 22 MB output stream out of L2/L3. (R11 win)
__device__ __forceinline__ void nt_store_v2f(float* p, v2f v){
    union { v2f f; unsigned long long u; } c; c.f = v;
    __builtin_nontemporal_store(c.u, (unsigned long long*)p);
}

// One sweep of N-1 chained gprods — PREFIX-NORM head formulation (R16).
// Key identity: the head channel after each gprod is exactly sqrt(C1^2+C2^2),
// so successive heads are a running L2 norm of the sweep's initial head values:
//   q_{i+1} = q_i + c_{i+1}^2 ,  h_{i+1} = sqrt(q_{i+1}) = q_{i+1} * rsq(q_{i+1})
// This turns the per-sweep serial core into a 13-step fma chain (~4 cyc/step);
// rsq + coefficient muls + all channel updates hang OFF the chain (full ILP),
// instead of each gprod's 30-40-cycle head chain feeding the next (R11 binder).
// Coefs: S=rsq(q_{i+1}); s1=c_{i+1}*S; s2=h_i*S; a1=copysign(s1,h_i);
//        a2n=-copysign(s2,c_{i+1});  x3 = a1*x1 + a2n*x2 ; x4 = s2*x1 + s1*x2.
// h_0 = c_0 (signed) so gprod 0 matches the original exactly; h>0 afterwards.
// logC == 0 exactly -> dropped. Lane0 st = cur, lane1 st = nxt; bb duplicated.
// Returns h_{N-1} (= final head value, positive) for phase-1's LC term.
template<int J, int C, int N, int OQ>
__device__ __forceinline__ float sweep(v2f (&st)[Gc][3], float (&bb)[Gc]){
    float h = bcast<OQ>(st[0][J][C]);   // signed first head
    float q = h * h;
#pragma unroll
    for (int i = 0; i < N - 1; ++i){
        const float cn  = bcast<OQ>(st[i + 1][J][C]);
        const float qn  = fmaf(cn, cn, q);
        const float S   = frsq(qn);              // off the q-chain
        const float s1  = cn * S;
        const float s2  = h * S;
        const float a1  = copysignf(s1, h);
        const float a2n = -copysignf(s2, cn);
        const v2f A1 = {a1, a1}, A2N = {a2n, a2n}, S1 = {s1, s1}, S2 = {s2, s2};
#pragma unroll
        for (int j = 0; j < 3; ++j){
            const v2f x = st[i][j], y = st[i + 1][j];
            st[i][j]     = __builtin_elementwise_fma(x, A1, y * A2N);
            st[i + 1][j] = __builtin_elementwise_fma(x, S2, y * S1);
        }
        {   // bias channel (scalar; bit-identical on both lanes)
            const float x = bb[i], y = bb[i + 1];
            bb[i]     = fmaf(x, a1, y * a2n);
            bb[i + 1] = fmaf(x, s2, y * s1);
        }
        q = qn;
        h = qn * S;                              // sqrt(qn) via q*rsq(q), >0
    }
    return h;
}

// (256,2): empirical cap = 256/min_waves = 128 VGPR — the proven no-spill tier
// (R11: VGPR 92). Grid 4096 waves = 4/SIMD resident.
__global__ void __launch_bounds__(256, 2)
gaussmerge_kernel(const float* __restrict__ cur_in,
                  const float* __restrict__ nxt_in,
                  const float* __restrict__ b_in,
                  float* __restrict__ out)
{
    const int tid = threadIdx.x;
    const int q = tid & 1;                          // 0: cur-owner, 1: nxt-owner
    const int p = blockIdx.x * 128 + (tid >> 1);    // point index

    v2f   st[Gc][3];
    float bb[Gc];

    const float* abase = (q ? nxt_in : cur_in) + (size_t)p * Hc;
    const float* bp    = b_in + p;
#pragma unroll
    for (int g = 0; g < Gc; ++g){
        // one 24-B record per lane: dwordx4 + dwordx2
        const float* rec = abase + (size_t)g * (NPc * Hc);
        const float4 A = *(const float4*)rec;
        const float2 B = *(const float2*)(rec + 4);
        st[g][0] = (v2f){A.x, A.y};
        st[g][1] = (v2f){A.z, A.w};
        st[g][2] = (v2f){B.x, B.y};
        bb[g] = bp[(size_t)g * NPc];
    }

    float LC = 0.0f;   // identical on both lanes now (h broadcast-derived)

    // ---- phase 1: head = cur[k] (lane0); k -> (J=k>>1, C=k&1); n = 14-k ----
    LC -= __logf(sweep<0, 0, 14, 0>(st, bb));
    LC -= __logf(sweep<0, 1, 13, 0>(st, bb));
    LC -= __logf(sweep<1, 0, 12, 0>(st, bb));
    LC -= __logf(sweep<1, 1, 11, 0>(st, bb));
    LC -= __logf(sweep<2, 0, 10, 0>(st, bb));
    LC -= __logf(sweep<2, 1,  9, 0>(st, bb));

    // ---- phase 2: head = nxt[k] (lane1); n = 8-k; popped slot m = 7-k ----
    float* outN = out;                               // (6, B, T, H)
    float* outB = out + (size_t)Hc * NPc * Hc;       // (6, B, T)
    float* outL = outB + (size_t)Hc * NPc;           // (B, T)

#define PH2(K, J, C, N)                                                         \
    (void)sweep<J, C, N, 1>(st, bb);                                            \
    {                                                                           \
        constexpr int m = 7 - (K);                                              \
        if (q) {                                                                \
            float* o = outN + (size_t)(K) * (NPc * Hc) + (size_t)p * Hc;        \
            nt_store_v2f(o,     st[m][0]);                                      \
            nt_store_v2f(o + 2, st[m][1]);                                      \
            nt_store_v2f(o + 4, st[m][2]);                                      \
        } else {                                                                \
            __builtin_nontemporal_store(bb[m], outB + (size_t)(K) * NPc + p);   \
        }                                                                       \
    }

    PH2(0, 0, 0, 8)
    PH2(1, 0, 1, 7)
    PH2(2, 1, 0, 6)
    PH2(3, 1, 1, 5)
    PH2(4, 2, 0, 4)
    PH2(5, 2, 1, 3)
#undef PH2

    // ---- epilogue: remaining biases (slots 0,1; identical on both lanes) ----
    LC += -0.5f * (LOG_2PI + bb[0] * bb[0]);
    LC += -0.5f * (LOG_2PI + bb[1] * bb[1]);
    if (q == 0) __builtin_nontemporal_store(LC, outL + p);
}

extern "C" void kernel_launch(void* const* d_in, const int* in_sizes, int n_in,
                              void* d_out, int out_size, void* d_ws, size_t ws_size,
                              hipStream_t stream) {
    const float* cur = (const float*)d_in[0];
    const float* nxt = (const float*)d_in[1];
    const float* bia = (const float*)d_in[2];
    float* out = (float*)d_out;

    // 2 threads per point: 256-thread blocks cover 128 points each.
    dim3 grid((NPc * 2) / 256), block(256);
    gaussmerge_kernel<<<grid, block, 0, stream>>>(cur, nxt, bia, out);
}

// Round 17
// 28.456 us; speedup vs baseline: 1.8275x; 1.0285x over previous
//
#include <hip/hip_runtime.h>

// G=14, B=64, T=2048, H=6
#define Gc 14
#define Hc 6
#define NPc (64*2048)          // B*T points
#define LOG_2PI 1.8378770664093453f

typedef float v2f __attribute__((ext_vector_type(2)));

__device__ __forceinline__ float frsq(float x){ return __builtin_amdgcn_rsqf(x); }
__device__ __forceinline__ float frcp(float x){ return __builtin_amdgcn_rcpf(x); }

// DPP quad_perm broadcast within lane pairs (1-cycle VALU, no LDS):
//   0xA0 = [0,0,2,2] -> pair gets EVEN lane's value; 0xF5 = [1,1,3,3] -> ODD lane's.
template<int CTRL>
__device__ __forceinline__ float dppf(float x){
    union { float f; int i; } u; u.f = x;
    u.i = __builtin_amdgcn_update_dpp(0, u.i, CTRL, 0xF, 0xF, true);
    return u.f;
}
template<int OQ>
__device__ __forceinline__ float bcast(float x){
    return (OQ == 0) ? dppf<0xA0>(x) : dppf<0xF5>(x);
}

__device__ __forceinline__ void nt_store_v2f(float* p, v2f v){
    union { v2f f; unsigned long long u; } c; c.f = v;
    __builtin_nontemporal_store(c.u, (unsigned long long*)p);
}

// ---- Householder sweep (R17) ----
// The reference's 90 chained 2x2 gprods are EXACT orthogonal rotations
// (a1^2+a2n^2 = s1^2+s2^2 = 1, rows orthogonal; hence logC == 0). Phase 1 is
// a Givens-QR of the cur block (positive diagonal), phase 2 a QR of the
// residual nxt block. By QR uniqueness (positive diag), outputs are invariant
// to the zeroing scheme -> use ONE Householder reflector per sweep:
//   q = ||head||^2, rn = ||head||, s = copysign(rn, h_pivot), v = head + s*e_pivot
//   beta = 1/(q + s*h_pivot);  col -= beta*(v.col) * v
// Pivot slot = N-1 (matches the reference's pop slot). Head column auto-zeroes
// (t=1 -> pivot -s). Phase-2 stored row is flipped by -sgn(s) to restore the
// reference's positive-diagonal sign convention.
// Lane0 holds cur banks, lane1 nxt banks; bb duplicated (bit-identical).
template<int J, int C, int N, int OQ, bool UPD_LAST>
__device__ __forceinline__ float hh_sweep(v2f (&st)[Gc][3], float (&bb)[Gc], float* sOut){
    // pass A: broadcast heads; accumulate q (2-way) and 7 column dots
    float q0 = 0.f, q1 = 0.f;
    v2f d0 = {0.f, 0.f}, d1 = {0.f, 0.f}, d2 = {0.f, 0.f};
    float db = 0.f;
    float hl = 0.f;
#pragma unroll
    for (int i = 0; i < N; ++i){
        const float hi = bcast<OQ>(st[i][J][C]);
        if (i & 1) q1 = fmaf(hi, hi, q1); else q0 = fmaf(hi, hi, q0);
        const v2f H = {hi, hi};
        d0 = __builtin_elementwise_fma(H, st[i][0], d0);
        d1 = __builtin_elementwise_fma(H, st[i][1], d1);
        d2 = __builtin_elementwise_fma(H, st[i][2], d2);
        db = fmaf(hi, bb[i], db);
        if (i == N - 1) hl = hi;
    }
    const float q    = q0 + q1;
    const float rn   = q * frsq(q);              // ||head||
    const float s    = copysignf(rn, hl);
    const float vl   = hl + s;                   // v at pivot (no cancellation)
    const float beta = frcp(fmaf(s, hl, q));     // 1/(q + s*hl) = 2/(v.v)
    // dot fix for pivot (v_pivot = hl + s, dots used hl): d += s * c[N-1]
    {
        const v2f S2 = {s, s};
        d0 = __builtin_elementwise_fma(S2, st[N - 1][0], d0);
        d1 = __builtin_elementwise_fma(S2, st[N - 1][1], d1);
        d2 = __builtin_elementwise_fma(S2, st[N - 1][2], d2);
        db = fmaf(s, bb[N - 1], db);
    }
    const v2f B2 = {beta, beta};
    const v2f t0 = d0 * B2, t1 = d1 * B2, t2 = d2 * B2;
    const float tb = db * beta;
    // pass B: rank-1 update c_i -= t * h_i (broadcast precedes slot i's writes)
#pragma unroll
    for (int i = 0; i < N - 1; ++i){
        const float hi = bcast<OQ>(st[i][J][C]);
        const v2f Hn = {-hi, -hi};
        st[i][0] = __builtin_elementwise_fma(t0, Hn, st[i][0]);
        st[i][1] = __builtin_elementwise_fma(t1, Hn, st[i][1]);
        st[i][2] = __builtin_elementwise_fma(t2, Hn, st[i][2]);
        bb[i] = fmaf(tb, -hi, bb[i]);
    }
    if (UPD_LAST){   // pivot slot needed only when it is stored (phase 2)
        const v2f Vn = {-vl, -vl};
        st[N - 1][0] = __builtin_elementwise_fma(t0, Vn, st[N - 1][0]);
        st[N - 1][1] = __builtin_elementwise_fma(t1, Vn, st[N - 1][1]);
        st[N - 1][2] = __builtin_elementwise_fma(t2, Vn, st[N - 1][2]);
        bb[N - 1] = fmaf(tb, -vl, bb[N - 1]);
    }
    *sOut = s;
    return rn;
}

// (256,2): empirical cap = 256/min_waves = 128 VGPR (proven no-spill tier).
__global__ void __launch_bounds__(256, 2)
gaussmerge_kernel(const float* __restrict__ cur_in,
                  const float* __restrict__ nxt_in,
                  const float* __restrict__ b_in,
                  float* __restrict__ out)
{
    const int tid = threadIdx.x;
    const int q = tid & 1;                          // 0: cur-owner, 1: nxt-owner
    const int p = blockIdx.x * 128 + (tid >> 1);    // point index

    v2f   st[Gc][3];
    float bb[Gc];

    const float* abase = (q ? nxt_in : cur_in) + (size_t)p * Hc;
    const float* bp    = b_in + p;
#pragma unroll
    for (int g = 0; g < Gc; ++g){
        const float* rec = abase + (size_t)g * (NPc * Hc);
        const float4 A = *(const float4*)rec;
        const float2 B = *(const float2*)(rec + 4);
        st[g][0] = (v2f){A.x, A.y};
        st[g][1] = (v2f){A.z, A.w};
        st[g][2] = (v2f){B.x, B.y};
        bb[g] = bp[(size_t)g * NPc];
    }

    float LC = 0.0f;   // rn broadcast-derived -> identical on both lanes
    float sdump;

    // ---- phase 1: head = cur[k] on lane0; (J,C) = (k>>1, k&1); N = 14-k ----
    LC -= __logf(hh_sweep<0, 0, 14, 0, false>(st, bb, &sdump));
    LC -= __logf(hh_sweep<0, 1, 13, 0, false>(st, bb, &sdump));
    LC -= __logf(hh_sweep<1, 0, 12, 0, false>(st, bb, &sdump));
    LC -= __logf(hh_sweep<1, 1, 11, 0, false>(st, bb, &sdump));
    LC -= __logf(hh_sweep<2, 0, 10, 0, false>(st, bb, &sdump));
    LC -= __logf(hh_sweep<2, 1,  9, 0, false>(st, bb, &sdump));

    // ---- phase 2: head = nxt[k] on lane1; N = 8-k; pivot slot m = 7-k ----
    float* outN = out;                               // (6, B, T, H)
    float* outB = out + (size_t)Hc * NPc * Hc;       // (6, B, T)
    float* outL = outB + (size_t)Hc * NPc;           // (B, T)

#define PH2(K, J, C, N)                                                         \
    {                                                                           \
        float s_;                                                               \
        (void)hh_sweep<J, C, N, 1, true>(st, bb, &s_);                          \
        constexpr int m = (N) - 1;                                              \
        const float flip = -copysignf(1.0f, s_);  /* positive-diag convention */\
        const v2f F = {flip, flip};                                             \
        if (q) {                                                                \
            float* o = outN + (size_t)(K) * (NPc * Hc) + (size_t)p * Hc;        \
            nt_store_v2f(o,     st[m][0] * F);                                  \
            nt_store_v2f(o + 2, st[m][1] * F);                                  \
            nt_store_v2f(o + 4, st[m][2] * F);                                  \
        } else {                                                                \
            __builtin_nontemporal_store(bb[m] * flip,                           \
                                        outB + (size_t)(K) * NPc + p);          \
        }                                                                       \
    }

    PH2(0, 0, 0, 8)
    PH2(1, 0, 1, 7)
    PH2(2, 1, 0, 6)
    PH2(3, 1, 1, 5)
    PH2(4, 2, 0, 4)
    PH2(5, 2, 1, 3)
#undef PH2

    // ---- epilogue: residual biases (slots 0,1; identical on both lanes) ----
    LC += -0.5f * (LOG_2PI + bb[0] * bb[0]);
    LC += -0.5f * (LOG_2PI + bb[1] * bb[1]);
    if (q == 0) __builtin_nontemporal_store(LC, outL + p);
}

extern "C" void kernel_launch(void* const* d_in, const int* in_sizes, int n_in,
                              void* d_out, int out_size, void* d_ws, size_t ws_size,
                              hipStream_t stream) {
    const float* cur = (const float*)d_in[0];
    const float* nxt = (const float*)d_in[1];
    const float* bia = (const float*)d_in[2];
    float* out = (float*)d_out;

    // 2 threads per point: 256-thread blocks cover 128 points each.
    dim3 grid((NPc * 2) / 256), block(256);
    gaussmerge_kernel<<<grid, block, 0, stream>>>(cur, nxt, bia, out);
}